// Round 11
// baseline (170.464 us; speedup 1.0000x reference)
//
#include <hip/hip_runtime.h>
#include <hip/hip_bf16.h>
#include <stdint.h>

#define D_MODEL 1024
#define NHEADS 16
#define HD 64
#define BB 4
#define TT 2048
#define MM (BB*TT)          // 8192 rows
#define NQKV (3*D_MODEL)    // 3072
#define KK D_MODEL          // 1024

typedef __attribute__((ext_vector_type(2))) float f32x2;
typedef __attribute__((ext_vector_type(4))) float f32x4;
typedef __attribute__((ext_vector_type(8))) short bf16x8;

__device__ __forceinline__ unsigned short f2bf(float x){
    union { __hip_bfloat16 h; unsigned short u; } c;
    c.h = __float2bfloat16(x);
    return c.u;
}

__device__ __forceinline__ void gload_lds16(const void* g, void* l){
    __builtin_amdgcn_global_load_lds(
        (const __attribute__((address_space(1))) unsigned int*)g,
        (__attribute__((address_space(3))) unsigned int*)l,
        16, 0, 0);
}

// ---------------- fused fp32 -> bf16 casts ----------------
#define N4_X  (MM*KK/4)
#define N4_WQ (NQKV*KK/4)
#define N4_WO (D_MODEL*D_MODEL/4)
__global__ void cast3_kernel(const float* __restrict__ x, const float* __restrict__ wq,
                             const float* __restrict__ wo,
                             unsigned short* __restrict__ xb, unsigned short* __restrict__ wqb,
                             unsigned short* __restrict__ wob){
    int i = blockIdx.x * blockDim.x + threadIdx.x;
    const float* src; unsigned short* dst; int j;
    if (i < N4_X)              { src = x;  dst = xb;  j = i; }
    else if (i < N4_X + N4_WQ) { src = wq; dst = wqb; j = i - N4_X; }
    else                       { src = wo; dst = wob; j = i - N4_X - N4_WQ; }
    float4 v = reinterpret_cast<const float4*>(src)[j];
    ushort4 o;
    o.x = f2bf(v.x); o.y = f2bf(v.y); o.z = f2bf(v.z); o.w = f2bf(v.w);
    reinterpret_cast<ushort4*>(dst)[j] = o;
}

// ============ counted-vmcnt ring-3 GEMM core (R5-exact, best measured) ============
// BM=256, BN=128, BK=32. 512 threads = 8 waves (2M x 4N). Per-wave out 128x32.
// LDS ring of 3 K-tiles (72 KB -> 2 blocks/CU, 16 waves/CU). vmcnt(3) counted.

#define GEMM_PROLOGUE(A_, B_)                                                   \
    const int tid = threadIdx.x;                                                \
    const int w = tid >> 6, l = tid & 63;                                       \
    const int wm = w >> 2, wn = w & 3;                                          \
    const int lr = l & 15, hi = l >> 4;                                         \
    f32x4 acc[8][2] = {};                                                       \
    const int c16 = hi ^ (lr & 3);                                              \
    const int base_a = (wm*128 + lr)*32 + c16*8;                                \
    const int base_b = (wn*32  + lr)*32 + c16*8;                                \
    const int g16 = ((tid & 3) ^ ((tid >> 2) & 3)) * 8;                         \
    const unsigned short* Aap = A_ + (size_t)(bm + (tid >> 2)) * KK + g16;      \
    const unsigned short* Bbp = B_ + (size_t)(bn + (tid >> 2)) * KK + g16;      \
    char* AsL = (char*)&As[0][0];                                               \
    char* BsL = (char*)&Bs[0][0];                                               \
    /* stage tiles 0,1 (order matters for vmcnt accounting) */                  \
    gload_lds16(Aap,                 AsL + tid*16);                             \
    gload_lds16(Aap + 128*KK,        AsL + 8192 + tid*16);                      \
    gload_lds16(Bbp,                 BsL + tid*16);                             \
    gload_lds16(Aap + 32,            AsL + 16384 + tid*16);                     \
    gload_lds16(Aap + 128*KK + 32,   AsL + 16384 + 8192 + tid*16);              \
    gload_lds16(Bbp + 32,            BsL + 8192 + tid*16);

#define GPHASE(VM, bc, bi, tnext, DOISSUE) do {                                 \
    asm volatile("s_waitcnt vmcnt(" #VM ")" ::: "memory");                      \
    __builtin_amdgcn_s_barrier();                                               \
    asm volatile("" ::: "memory");                                              \
    bf16x8 af[8], bfn[2];                                                       \
    _Pragma("unroll")                                                           \
    for (int m = 0; m < 8; m++)                                                 \
        af[m] = *reinterpret_cast<const bf16x8*>(&As[bc][base_a + m*512]);      \
    _Pragma("unroll")                                                           \
    for (int n = 0; n < 2; n++)                                                 \
        bfn[n] = *reinterpret_cast<const bf16x8*>(&Bs[bc][base_b + n*512]);     \
    if (DOISSUE) {                                                              \
        gload_lds16(Aap + (tnext)*32,           AsL + (bi)*16384 + tid*16);     \
        gload_lds16(Aap + 128*KK + (tnext)*32,  AsL + (bi)*16384 + 8192 + tid*16);\
        gload_lds16(Bbp + (tnext)*32,           BsL + (bi)*8192 + tid*16);      \
    }                                                                           \
    __builtin_amdgcn_s_setprio(1);                                              \
    _Pragma("unroll")                                                           \
    for (int m = 0; m < 8; m++) {                                               \
        acc[m][0] = __builtin_amdgcn_mfma_f32_16x16x32_bf16(af[m], bfn[0], acc[m][0], 0, 0, 0); \
        acc[m][1] = __builtin_amdgcn_mfma_f32_16x16x32_bf16(af[m], bfn[1], acc[m][1], 0, 0, 0); \
    }                                                                           \
    __builtin_amdgcn_s_setprio(0);                                              \
} while(0)

#define GEMM_MAINLOOP()                                                         \
    for (int t3 = 0; t3 < 30; t3 += 3) {                                        \
        GPHASE(3, 0, 2, t3+2, 1);                                               \
        GPHASE(3, 1, 0, t3+3, 1);                                               \
        GPHASE(3, 2, 1, t3+4, 1);                                               \
    }                                                                           \
    GPHASE(3, 0, 2, 0, 0);                                                      \
    GPHASE(0, 1, 2, 0, 0);

// ---------------- QKV projection GEMM ----------------
__global__ __launch_bounds__(512, 4) void gemm_qkv(
    const unsigned short* __restrict__ A, const unsigned short* __restrict__ Bw,
    const float* __restrict__ bias,
    unsigned short* __restrict__ qb, unsigned short* __restrict__ kb,
    unsigned short* __restrict__ vtb)
{
    __shared__ alignas(16) unsigned short As[3][256*32];
    __shared__ alignas(16) unsigned short Bs[3][128*32];
    const int tiles_n = NQKV/128;                 // 24
    int nwg = gridDim.x;
    int orig = blockIdx.x;
    int bid = (orig & 7) * (nwg >> 3) + (orig >> 3);
    int bm = (bid / tiles_n) * 256;
    int bn = (bid % tiles_n) * 128;

    GEMM_PROLOGUE(A, Bw)
    GEMM_MAINLOOP()

    #pragma unroll
    for (int m = 0; m < 8; m++) {
        int gm = bm + wm*128 + m*16 + hi*4;       // +r
        int b  = gm >> 11;
        int t  = gm & 2047;
        #pragma unroll
        for (int n = 0; n < 2; n++) {
            int gn = bn + wn*32 + n*16 + lr;
            float bv = bias[gn];
            int sec = gn >> 10;               // 0=Q 1=K 2=V
            int nn  = gn & 1023;
            int h = nn >> 6, d = nn & 63;
            int bh = b * NHEADS + h;
            if (sec == 2) {
                ushort4 pk;
                pk.x = f2bf(acc[m][n][0] + bv);
                pk.y = f2bf(acc[m][n][1] + bv);
                pk.z = f2bf(acc[m][n][2] + bv);
                pk.w = f2bf(acc[m][n][3] + bv);
                *reinterpret_cast<ushort4*>(&vtb[((size_t)bh*HD + d)*TT + t]) = pk;
            } else {
                unsigned short* dst = (sec == 0) ? qb : kb;
                #pragma unroll
                for (int r = 0; r < 4; r++)
                    dst[((size_t)bh*TT + t + r)*HD + d] = f2bf(acc[m][n][r] + bv);
            }
        }
    }
}

// ---------------- output projection GEMM ----------------
__global__ __launch_bounds__(512, 4) void gemm_out(
    const unsigned short* __restrict__ A, const unsigned short* __restrict__ Bw,
    const float* __restrict__ bias, float* __restrict__ out)
{
    __shared__ alignas(16) unsigned short As[3][256*32];
    __shared__ alignas(16) unsigned short Bs[3][128*32];
    const int tiles_n = D_MODEL/128;              // 8
    int nwg = gridDim.x;
    int orig = blockIdx.x;
    int bid = (orig & 7) * (nwg >> 3) + (orig >> 3);
    int bm = (bid / tiles_n) * 256;
    int bn = (bid % tiles_n) * 128;

    GEMM_PROLOGUE(A, Bw)
    GEMM_MAINLOOP()

    #pragma unroll
    for (int m = 0; m < 8; m++) {
        int gm = bm + wm*128 + m*16 + hi*4;
        #pragma unroll
        for (int n = 0; n < 2; n++) {
            int gn = bn + wn*32 + n*16 + lr;
            float bv = bias[gn];
            #pragma unroll
            for (int r = 0; r < 4; r++)
                out[(size_t)(gm + r)*D_MODEL + gn] = acc[m][n][r] + bv;
        }
    }
}

// ---------------- causal flash attention: paired q-tiles for exact balance ----------------
// grid (bh, 8); block p runs qt = 15-p then qt = p -> every block = 17 pair-units.
__global__ __launch_bounds__(512) void attn_kernel(
    const unsigned short* __restrict__ qb, const unsigned short* __restrict__ kb,
    const unsigned short* __restrict__ vtb, unsigned short* __restrict__ ao)
{
    __shared__ alignas(16) unsigned short Kt[4][64*64];
    __shared__ alignas(16) unsigned short Vt[4][64*64];
    __shared__ alignas(16) unsigned short Pl[8][16*64];

    const int bh = blockIdx.x;
    const int pidx = blockIdx.y;                   // 0..7
    const int tid = threadIdx.x;
    const int w = tid >> 6, l = tid & 63;
    const int lr = l & 15, hi = l >> 4;

    const unsigned short* Kg = kb  + (size_t)bh*TT*HD;
    const unsigned short* Vg = vtb + (size_t)bh*HD*TT;

    const int srow = w*8 + (l >> 3);
    const int sc16 = (l & 7) ^ (srow & 7);
    char* KS0 = (char*)&Kt[0][0] + w*1024;  char* KS1 = (char*)&Kt[1][0] + w*1024;
    char* KS2 = (char*)&Kt[2][0] + w*1024;  char* KS3 = (char*)&Kt[3][0] + w*1024;
    char* VS0 = (char*)&Vt[0][0] + w*1024;  char* VS1 = (char*)&Vt[1][0] + w*1024;
    char* VS2 = (char*)&Vt[2][0] + w*1024;  char* VS3 = (char*)&Vt[3][0] + w*1024;

    const float sc = 0.125f * 1.4426950408889634f;
    const float THR = 8.0f / sc;
    const int swp = (lr & 7) << 4;
    char* Pw = (char*)&Pl[w][0];
    const int b = bh >> 4, h = bh & 15;

    for (int run = 0; run < 2; ++run) {
        const int qt = run == 0 ? (15 - pidx) : pidx;   // big tile first
        const int qbase = qt * 128;
        const int qrow  = qbase + w*16;
        const int npairs = qt + 1;
        const int qg = qrow + lr;

        const unsigned short* Qp = qb + ((size_t)bh*TT + qrow) * HD;
        bf16x8 qf0 = *reinterpret_cast<const bf16x8*>(Qp + lr*HD + hi*8);
        bf16x8 qf1 = *reinterpret_cast<const bf16x8*>(Qp + lr*HD + 32 + hi*8);

        gload_lds16(Kg + (size_t)srow*HD + sc16*8,        KS0);
        gload_lds16(Vg + (size_t)srow*TT + sc16*8,        VS0);
        gload_lds16(Kg + (size_t)(64 + srow)*HD + sc16*8, KS1);
        gload_lds16(Vg + (size_t)srow*TT + 64 + sc16*8,   VS1);
        __syncthreads();

        float mS = -3e38f, lS = 0.f;
        f32x4 o[4] = {};

        for (int j = 0; j < npairs; ++j) {
            const int ph = j & 1;
            const char* Ka = ph ? (const char*)&Kt[2][0] : (const char*)&Kt[0][0];
            const char* Kc = ph ? (const char*)&Kt[3][0] : (const char*)&Kt[1][0];
            const char* Va = ph ? (const char*)&Vt[2][0] : (const char*)&Vt[0][0];
            const char* Vc = ph ? (const char*)&Vt[3][0] : (const char*)&Vt[1][0];
            if (j + 1 < npairs) {
                const int tn = 2*j + 2;
                char* kd0 = ph ? KS0 : KS2;  char* kd1 = ph ? KS1 : KS3;
                char* vd0 = ph ? VS0 : VS2;  char* vd1 = ph ? VS1 : VS3;
                gload_lds16(Kg + (size_t)(tn*64 + srow)*HD + sc16*8,      kd0);
                gload_lds16(Vg + (size_t)srow*TT + tn*64 + sc16*8,        vd0);
                gload_lds16(Kg + (size_t)(tn*64 + 64 + srow)*HD + sc16*8, kd1);
                gload_lds16(Vg + (size_t)srow*TT + tn*64 + 64 + sc16*8,   vd1);
            }
            const int kba = 2*j*64;
            const int kbb = kba + 64;
            const bool cb = (kbb <= qrow + 15);

            f32x4 sa4[4] = {}, sb4[4] = {};
            __builtin_amdgcn_s_setprio(1);
            #pragma unroll
            for (int n = 0; n < 4; n++) {
                int rb = (n*16 + lr) * 128;
                bf16x8 k0 = *reinterpret_cast<const bf16x8*>(Ka + rb + (( 0 + hi*16) ^ swp));
                bf16x8 k1 = *reinterpret_cast<const bf16x8*>(Ka + rb + ((64 + hi*16) ^ swp));
                sa4[n] = __builtin_amdgcn_mfma_f32_16x16x32_bf16(k0, qf0, sa4[n], 0, 0, 0);
                sa4[n] = __builtin_amdgcn_mfma_f32_16x16x32_bf16(k1, qf1, sa4[n], 0, 0, 0);
            }
            if (cb) {
                #pragma unroll
                for (int n = 0; n < 4; n++) {
                    int rb = (n*16 + lr) * 128;
                    bf16x8 k0 = *reinterpret_cast<const bf16x8*>(Kc + rb + (( 0 + hi*16) ^ swp));
                    bf16x8 k1 = *reinterpret_cast<const bf16x8*>(Kc + rb + ((64 + hi*16) ^ swp));
                    sb4[n] = __builtin_amdgcn_mfma_f32_16x16x32_bf16(k0, qf0, sb4[n], 0, 0, 0);
                    sb4[n] = __builtin_amdgcn_mfma_f32_16x16x32_bf16(k1, qf1, sb4[n], 0, 0, 0);
                }
            }
            __builtin_amdgcn_s_setprio(0);

            if (kba + 63 > qrow) {
                #pragma unroll
                for (int n = 0; n < 4; n++)
                    #pragma unroll
                    for (int r = 0; r < 4; r++)
                        if (kba + n*16 + hi*4 + r > qg) sa4[n][r] = -3e38f;
            }
            if (cb && kbb + 63 > qrow) {
                #pragma unroll
                for (int n = 0; n < 4; n++)
                    #pragma unroll
                    for (int r = 0; r < 4; r++)
                        if (kbb + n*16 + hi*4 + r > qg) sb4[n][r] = -3e38f;
            }

            // per-q-row max over the pair: packed-f32 tree
            f32x2 m2;
            {
                f32x2 x0 = __builtin_shufflevector(sa4[0], sa4[0], 0, 1);
                f32x2 x1 = __builtin_shufflevector(sa4[0], sa4[0], 2, 3);
                m2 = __builtin_elementwise_max(x0, x1);
                #pragma unroll
                for (int n = 1; n < 4; n++) {
                    f32x2 y0 = __builtin_shufflevector(sa4[n], sa4[n], 0, 1);
                    f32x2 y1 = __builtin_shufflevector(sa4[n], sa4[n], 2, 3);
                    m2 = __builtin_elementwise_max(m2, __builtin_elementwise_max(y0, y1));
                }
                if (cb) {
                    #pragma unroll
                    for (int n = 0; n < 4; n++) {
                        f32x2 y0 = __builtin_shufflevector(sb4[n], sb4[n], 0, 1);
                        f32x2 y1 = __builtin_shufflevector(sb4[n], sb4[n], 2, 3);
                        m2 = __builtin_elementwise_max(m2, __builtin_elementwise_max(y0, y1));
                    }
                }
            }
            float rm = fmaxf(m2[0], m2[1]);
            rm = fmaxf(rm, __shfl_xor(rm, 16, 64));
            rm = fmaxf(rm, __shfl_xor(rm, 32, 64));
            if (!__all(rm - mS <= THR)) {
                float newm = fmaxf(mS, rm);
                float al = exp2f(sc * (mS - newm));
                mS = newm;
                lS *= al;
                #pragma unroll
                for (int r = 0; r < 4; r++) {
                    float alr = __shfl(al, hi*4 + r, 64);
                    o[0][r] *= alr; o[1][r] *= alr; o[2][r] *= alr; o[3][r] *= alr;
                }
            }
            const float c0 = sc * mS;
            const f32x2 sc2 = {sc, sc};
            const f32x2 cc2 = {-c0, -c0};
            f32x2 rs2 = {0.f, 0.f};

            #pragma unroll
            for (int n = 0; n < 4; n++) {
                f32x2 lo = __builtin_shufflevector(sa4[n], sa4[n], 0, 1);
                f32x2 hif = __builtin_shufflevector(sa4[n], sa4[n], 2, 3);
                lo  = __builtin_elementwise_fma(lo,  sc2, cc2);
                hif = __builtin_elementwise_fma(hif, sc2, cc2);
                f32x2 plo = {exp2f(lo[0]),  exp2f(lo[1])};
                f32x2 phi = {exp2f(hif[0]), exp2f(hif[1])};
                rs2 += plo + phi;
                ushort4 u;
                u.x = f2bf(plo[0]); u.y = f2bf(plo[1]);
                u.z = f2bf(phi[0]); u.w = f2bf(phi[1]);
                *reinterpret_cast<ushort4*>(Pw + (lr*128 + ((n*32 + hi*8) ^ swp))) = u;
            }
            ushort4 ub[4];
            if (cb) {
                #pragma unroll
                for (int n = 0; n < 4; n++) {
                    f32x2 lo = __builtin_shufflevector(sb4[n], sb4[n], 0, 1);
                    f32x2 hif = __builtin_shufflevector(sb4[n], sb4[n], 2, 3);
                    lo  = __builtin_elementwise_fma(lo,  sc2, cc2);
                    hif = __builtin_elementwise_fma(hif, sc2, cc2);
                    f32x2 plo = {exp2f(lo[0]),  exp2f(lo[1])};
                    f32x2 phi = {exp2f(hif[0]), exp2f(hif[1])};
                    rs2 += plo + phi;
                    ub[n].x = f2bf(plo[0]); ub[n].y = f2bf(plo[1]);
                    ub[n].z = f2bf(phi[0]); ub[n].w = f2bf(phi[1]);
                }
            }
            float rs = rs2[0] + rs2[1];
            rs += __shfl_xor(rs, 16, 64);
            rs += __shfl_xor(rs, 32, 64);
            lS += rs;

            {
                bf16x8 pa0 = *reinterpret_cast<const bf16x8*>(Pw + (lr*128 + (( 0 + hi*16) ^ swp)));
                bf16x8 pa1 = *reinterpret_cast<const bf16x8*>(Pw + (lr*128 + ((64 + hi*16) ^ swp)));
                __builtin_amdgcn_s_setprio(1);
                #pragma unroll
                for (int nd = 0; nd < 4; nd++) {
                    int rb = (nd*16 + lr) * 128;
                    bf16x8 v0 = *reinterpret_cast<const bf16x8*>(Va + rb + (( 0 + hi*16) ^ swp));
                    bf16x8 v1 = *reinterpret_cast<const bf16x8*>(Va + rb + ((64 + hi*16) ^ swp));
                    o[nd] = __builtin_amdgcn_mfma_f32_16x16x32_bf16(pa0, v0, o[nd], 0, 0, 0);
                    o[nd] = __builtin_amdgcn_mfma_f32_16x16x32_bf16(pa1, v1, o[nd], 0, 0, 0);
                }
                __builtin_amdgcn_s_setprio(0);
            }
            if (cb) {
                #pragma unroll
                for (int n = 0; n < 4; n++)
                    *reinterpret_cast<ushort4*>(Pw + (lr*128 + ((n*32 + hi*8) ^ swp))) = ub[n];
                bf16x8 pa0 = *reinterpret_cast<const bf16x8*>(Pw + (lr*128 + (( 0 + hi*16) ^ swp)));
                bf16x8 pa1 = *reinterpret_cast<const bf16x8*>(Pw + (lr*128 + ((64 + hi*16) ^ swp)));
                __builtin_amdgcn_s_setprio(1);
                #pragma unroll
                for (int nd = 0; nd < 4; nd++) {
                    int rb = (nd*16 + lr) * 128;
                    bf16x8 v0 = *reinterpret_cast<const bf16x8*>(Vc + rb + (( 0 + hi*16) ^ swp));
                    bf16x8 v1 = *reinterpret_cast<const bf16x8*>(Vc + rb + ((64 + hi*16) ^ swp));
                    o[nd] = __builtin_amdgcn_mfma_f32_16x16x32_bf16(pa0, v0, o[nd], 0, 0, 0);
                    o[nd] = __builtin_amdgcn_mfma_f32_16x16x32_bf16(pa1, v1, o[nd], 0, 0, 0);
                }
                __builtin_amdgcn_s_setprio(0);
            }
            __syncthreads();
        }

        // epilogue for this q-tile
        float inv = 1.0f / lS;
        #pragma unroll
        for (int r = 0; r < 4; r++) {
            float invr = __shfl(inv, hi*4 + r, 64);
            int t = qrow + hi*4 + r;
            #pragma unroll
            for (int nd = 0; nd < 4; nd++) {
                float val = o[nd][r] * invr;
                ao[((size_t)b*TT + t)*D_MODEL + h*HD + nd*16 + lr] = f2bf(val);
            }
        }
    }
}

extern "C" void kernel_launch(void* const* d_in, const int* in_sizes, int n_in,
                              void* d_out, int out_size, void* d_ws, size_t ws_size,
                              hipStream_t stream) {
    const float* x     = (const float*)d_in[0];
    const float* w_qkv = (const float*)d_in[1];
    const float* b_qkv = (const float*)d_in[2];
    const float* w_out = (const float*)d_in[3];
    const float* b_out = (const float*)d_in[4];
    float* out = (float*)d_out;

    char* ws = (char*)d_ws;
    unsigned short* xbf   = (unsigned short*)(ws);                         // 16 MB
    unsigned short* wqkvb = (unsigned short*)(ws + (size_t)16777216);      // 6 MB
    unsigned short* woutb = (unsigned short*)(ws + (size_t)23068672);      // 2 MB
    unsigned short* qb    = (unsigned short*)(ws + (size_t)25165824);      // 16 MB
    unsigned short* kb    = (unsigned short*)(ws + (size_t)41943040);      // 16 MB
    unsigned short* vtb   = (unsigned short*)(ws + (size_t)58720256);      // 16 MB
    unsigned short* aob   = xbf;  // alias: x_bf16 dead after gemm_qkv

    cast3_kernel<<<(N4_X + N4_WQ + N4_WO)/256, 256, 0, stream>>>(x, w_qkv, w_out, xbf, wqkvb, woutb);

    gemm_qkv<<<(MM/256)*(NQKV/128), 512, 0, stream>>>(xbf, wqkvb, b_qkv, qb, kb, vtb);
    attn_kernel<<<dim3(BB*NHEADS, 8), 512, 0, stream>>>(qb, kb, vtb, aob);
    gemm_out<<<(MM/256)*(D_MODEL/128), 512, 0, stream>>>(aob, woutb, b_out, out);
}

// Round 12
// 167.909 us; speedup vs baseline: 1.0152x; 1.0152x over previous
//
#include <hip/hip_runtime.h>
#include <hip/hip_bf16.h>
#include <stdint.h>

#define D_MODEL 1024
#define NHEADS 16
#define HD 64
#define BB 4
#define TT 2048
#define MM (BB*TT)          // 8192 rows
#define NQKV (3*D_MODEL)    // 3072
#define KK D_MODEL          // 1024

typedef __attribute__((ext_vector_type(2))) float f32x2;
typedef __attribute__((ext_vector_type(4))) float f32x4;
typedef __attribute__((ext_vector_type(8))) short bf16x8;

__device__ __forceinline__ unsigned short f2bf(float x){
    union { __hip_bfloat16 h; unsigned short u; } c;
    c.h = __float2bfloat16(x);
    return c.u;
}

__device__ __forceinline__ void gload_lds16(const void* g, void* l){
    __builtin_amdgcn_global_load_lds(
        (const __attribute__((address_space(1))) unsigned int*)g,
        (__attribute__((address_space(3))) unsigned int*)l,
        16, 0, 0);
}

// ---------------- fused fp32 -> bf16 casts ----------------
#define N4_X  (MM*KK/4)
#define N4_WQ (NQKV*KK/4)
#define N4_WO (D_MODEL*D_MODEL/4)
__global__ void cast3_kernel(const float* __restrict__ x, const float* __restrict__ wq,
                             const float* __restrict__ wo,
                             unsigned short* __restrict__ xb, unsigned short* __restrict__ wqb,
                             unsigned short* __restrict__ wob){
    int i = blockIdx.x * blockDim.x + threadIdx.x;
    const float* src; unsigned short* dst; int j;
    if (i < N4_X)              { src = x;  dst = xb;  j = i; }
    else if (i < N4_X + N4_WQ) { src = wq; dst = wqb; j = i - N4_X; }
    else                       { src = wo; dst = wob; j = i - N4_X - N4_WQ; }
    float4 v = reinterpret_cast<const float4*>(src)[j];
    ushort4 o;
    o.x = f2bf(v.x); o.y = f2bf(v.y); o.z = f2bf(v.z); o.w = f2bf(v.w);
    reinterpret_cast<ushort4*>(dst)[j] = o;
}

// ============ counted-vmcnt ring-3 GEMM core (R5-exact, best measured) ============
// BM=256, BN=128, BK=32. 512 threads = 8 waves (2M x 4N). Per-wave out 128x32.
// LDS ring of 3 K-tiles (72 KB -> 2 blocks/CU, 16 waves/CU). vmcnt(3) counted.

#define GEMM_PROLOGUE(A_, B_)                                                   \
    const int tid = threadIdx.x;                                                \
    const int w = tid >> 6, l = tid & 63;                                       \
    const int wm = w >> 2, wn = w & 3;                                          \
    const int lr = l & 15, hi = l >> 4;                                         \
    f32x4 acc[8][2] = {};                                                       \
    const int c16 = hi ^ (lr & 3);                                              \
    const int base_a = (wm*128 + lr)*32 + c16*8;                                \
    const int base_b = (wn*32  + lr)*32 + c16*8;                                \
    const int g16 = ((tid & 3) ^ ((tid >> 2) & 3)) * 8;                         \
    const unsigned short* Aap = A_ + (size_t)(bm + (tid >> 2)) * KK + g16;      \
    const unsigned short* Bbp = B_ + (size_t)(bn + (tid >> 2)) * KK + g16;      \
    char* AsL = (char*)&As[0][0];                                               \
    char* BsL = (char*)&Bs[0][0];                                               \
    /* stage tiles 0,1 (order matters for vmcnt accounting) */                  \
    gload_lds16(Aap,                 AsL + tid*16);                             \
    gload_lds16(Aap + 128*KK,        AsL + 8192 + tid*16);                      \
    gload_lds16(Bbp,                 BsL + tid*16);                             \
    gload_lds16(Aap + 32,            AsL + 16384 + tid*16);                     \
    gload_lds16(Aap + 128*KK + 32,   AsL + 16384 + 8192 + tid*16);              \
    gload_lds16(Bbp + 32,            BsL + 8192 + tid*16);

#define GPHASE(VM, bc, bi, tnext, DOISSUE) do {                                 \
    asm volatile("s_waitcnt vmcnt(" #VM ")" ::: "memory");                      \
    __builtin_amdgcn_s_barrier();                                               \
    asm volatile("" ::: "memory");                                              \
    bf16x8 af[8], bfn[2];                                                       \
    _Pragma("unroll")                                                           \
    for (int m = 0; m < 8; m++)                                                 \
        af[m] = *reinterpret_cast<const bf16x8*>(&As[bc][base_a + m*512]);      \
    _Pragma("unroll")                                                           \
    for (int n = 0; n < 2; n++)                                                 \
        bfn[n] = *reinterpret_cast<const bf16x8*>(&Bs[bc][base_b + n*512]);     \
    if (DOISSUE) {                                                              \
        gload_lds16(Aap + (tnext)*32,           AsL + (bi)*16384 + tid*16);     \
        gload_lds16(Aap + 128*KK + (tnext)*32,  AsL + (bi)*16384 + 8192 + tid*16);\
        gload_lds16(Bbp + (tnext)*32,           BsL + (bi)*8192 + tid*16);      \
    }                                                                           \
    __builtin_amdgcn_s_setprio(1);                                              \
    _Pragma("unroll")                                                           \
    for (int m = 0; m < 8; m++) {                                               \
        acc[m][0] = __builtin_amdgcn_mfma_f32_16x16x32_bf16(af[m], bfn[0], acc[m][0], 0, 0, 0); \
        acc[m][1] = __builtin_amdgcn_mfma_f32_16x16x32_bf16(af[m], bfn[1], acc[m][1], 0, 0, 0); \
    }                                                                           \
    __builtin_amdgcn_s_setprio(0);                                              \
} while(0)

#define GEMM_MAINLOOP()                                                         \
    for (int t3 = 0; t3 < 30; t3 += 3) {                                        \
        GPHASE(3, 0, 2, t3+2, 1);                                               \
        GPHASE(3, 1, 0, t3+3, 1);                                               \
        GPHASE(3, 2, 1, t3+4, 1);                                               \
    }                                                                           \
    GPHASE(3, 0, 2, 0, 0);                                                      \
    GPHASE(0, 1, 2, 0, 0);

// ---------------- QKV projection GEMM ----------------
__global__ __launch_bounds__(512, 4) void gemm_qkv(
    const unsigned short* __restrict__ A, const unsigned short* __restrict__ Bw,
    const float* __restrict__ bias,
    unsigned short* __restrict__ qb, unsigned short* __restrict__ kb,
    unsigned short* __restrict__ vtb)
{
    __shared__ alignas(16) unsigned short As[3][256*32];
    __shared__ alignas(16) unsigned short Bs[3][128*32];
    const int tiles_n = NQKV/128;                 // 24
    int nwg = gridDim.x;
    int orig = blockIdx.x;
    int bid = (orig & 7) * (nwg >> 3) + (orig >> 3);
    int bm = (bid / tiles_n) * 256;
    int bn = (bid % tiles_n) * 128;

    GEMM_PROLOGUE(A, Bw)
    GEMM_MAINLOOP()

    #pragma unroll
    for (int m = 0; m < 8; m++) {
        int gm = bm + wm*128 + m*16 + hi*4;       // +r
        int b  = gm >> 11;
        int t  = gm & 2047;
        #pragma unroll
        for (int n = 0; n < 2; n++) {
            int gn = bn + wn*32 + n*16 + lr;
            float bv = bias[gn];
            int sec = gn >> 10;               // 0=Q 1=K 2=V
            int nn  = gn & 1023;
            int h = nn >> 6, d = nn & 63;
            int bh = b * NHEADS + h;
            if (sec == 2) {
                ushort4 pk;
                pk.x = f2bf(acc[m][n][0] + bv);
                pk.y = f2bf(acc[m][n][1] + bv);
                pk.z = f2bf(acc[m][n][2] + bv);
                pk.w = f2bf(acc[m][n][3] + bv);
                *reinterpret_cast<ushort4*>(&vtb[((size_t)bh*HD + d)*TT + t]) = pk;
            } else {
                unsigned short* dst = (sec == 0) ? qb : kb;
                #pragma unroll
                for (int r = 0; r < 4; r++)
                    dst[((size_t)bh*TT + t + r)*HD + d] = f2bf(acc[m][n][r] + bv);
            }
        }
    }
}

// ---------------- output projection GEMM ----------------
__global__ __launch_bounds__(512, 4) void gemm_out(
    const unsigned short* __restrict__ A, const unsigned short* __restrict__ Bw,
    const float* __restrict__ bias, float* __restrict__ out)
{
    __shared__ alignas(16) unsigned short As[3][256*32];
    __shared__ alignas(16) unsigned short Bs[3][128*32];
    const int tiles_n = D_MODEL/128;              // 8
    int nwg = gridDim.x;
    int orig = blockIdx.x;
    int bid = (orig & 7) * (nwg >> 3) + (orig >> 3);
    int bm = (bid / tiles_n) * 256;
    int bn = (bid % tiles_n) * 128;

    GEMM_PROLOGUE(A, Bw)
    GEMM_MAINLOOP()

    #pragma unroll
    for (int m = 0; m < 8; m++) {
        int gm = bm + wm*128 + m*16 + hi*4;
        #pragma unroll
        for (int n = 0; n < 2; n++) {
            int gn = bn + wn*32 + n*16 + lr;
            float bv = bias[gn];
            #pragma unroll
            for (int r = 0; r < 4; r++)
                out[(size_t)(gm + r)*D_MODEL + gn] = acc[m][n][r] + bv;
        }
    }
}

// ---------------- causal flash attention: paired k-tiles + packed-f32 softmax ----------------
__global__ __launch_bounds__(512) void attn_kernel(
    const unsigned short* __restrict__ qb, const unsigned short* __restrict__ kb,
    const unsigned short* __restrict__ vtb, unsigned short* __restrict__ ao)
{
    __shared__ alignas(16) unsigned short Kt[4][64*64];
    __shared__ alignas(16) unsigned short Vt[4][64*64];
    __shared__ alignas(16) unsigned short Pl[8][16*64];

    const int bh = blockIdx.x;
    const int qt = (gridDim.y - 1) - blockIdx.y;   // big tiles first
    const int tid = threadIdx.x;
    const int w = tid >> 6, l = tid & 63;
    const int lr = l & 15, hi = l >> 4;

    const int qbase = qt * 128;
    const int qrow  = qbase + w*16;
    const int npairs = qt + 1;

    const unsigned short* Qp = qb + ((size_t)bh*TT + qrow) * HD;
    bf16x8 qf0 = *reinterpret_cast<const bf16x8*>(Qp + lr*HD + hi*8);
    bf16x8 qf1 = *reinterpret_cast<const bf16x8*>(Qp + lr*HD + 32 + hi*8);

    const unsigned short* Kg = kb  + (size_t)bh*TT*HD;
    const unsigned short* Vg = vtb + (size_t)bh*HD*TT;

    const int srow = w*8 + (l >> 3);
    const int sc16 = (l & 7) ^ (srow & 7);
    char* KS0 = (char*)&Kt[0][0] + w*1024;  char* KS1 = (char*)&Kt[1][0] + w*1024;
    char* KS2 = (char*)&Kt[2][0] + w*1024;  char* KS3 = (char*)&Kt[3][0] + w*1024;
    char* VS0 = (char*)&Vt[0][0] + w*1024;  char* VS1 = (char*)&Vt[1][0] + w*1024;
    char* VS2 = (char*)&Vt[2][0] + w*1024;  char* VS3 = (char*)&Vt[3][0] + w*1024;

    gload_lds16(Kg + (size_t)srow*HD + sc16*8,        KS0);
    gload_lds16(Vg + (size_t)srow*TT + sc16*8,        VS0);
    gload_lds16(Kg + (size_t)(64 + srow)*HD + sc16*8, KS1);
    gload_lds16(Vg + (size_t)srow*TT + 64 + sc16*8,   VS1);
    __syncthreads();

    float mS = -3e38f, lS = 0.f;
    f32x4 o[4] = {};
    const float sc = 0.125f * 1.4426950408889634f;
    const float THR = 8.0f / sc;
    const int qg = qrow + lr;
    const int swp = (lr & 7) << 4;
    char* Pw = (char*)&Pl[w][0];

    for (int j = 0; j < npairs; ++j) {
        const int ph = j & 1;
        const char* Ka = ph ? (const char*)&Kt[2][0] : (const char*)&Kt[0][0];
        const char* Kc = ph ? (const char*)&Kt[3][0] : (const char*)&Kt[1][0];
        const char* Va = ph ? (const char*)&Vt[2][0] : (const char*)&Vt[0][0];
        const char* Vc = ph ? (const char*)&Vt[3][0] : (const char*)&Vt[1][0];
        if (j + 1 < npairs) {
            const int tn = 2*j + 2;
            char* kd0 = ph ? KS0 : KS2;  char* kd1 = ph ? KS1 : KS3;
            char* vd0 = ph ? VS0 : VS2;  char* vd1 = ph ? VS1 : VS3;
            gload_lds16(Kg + (size_t)(tn*64 + srow)*HD + sc16*8,      kd0);
            gload_lds16(Vg + (size_t)srow*TT + tn*64 + sc16*8,        vd0);
            gload_lds16(Kg + (size_t)(tn*64 + 64 + srow)*HD + sc16*8, kd1);
            gload_lds16(Vg + (size_t)srow*TT + tn*64 + 64 + sc16*8,   vd1);
        }
        const int kba = 2*j*64;
        const int kbb = kba + 64;
        const bool cb = (kbb <= qrow + 15);

        f32x4 sa4[4] = {}, sb4[4] = {};
        __builtin_amdgcn_s_setprio(1);
        #pragma unroll
        for (int n = 0; n < 4; n++) {
            int rb = (n*16 + lr) * 128;
            bf16x8 k0 = *reinterpret_cast<const bf16x8*>(Ka + rb + (( 0 + hi*16) ^ swp));
            bf16x8 k1 = *reinterpret_cast<const bf16x8*>(Ka + rb + ((64 + hi*16) ^ swp));
            sa4[n] = __builtin_amdgcn_mfma_f32_16x16x32_bf16(k0, qf0, sa4[n], 0, 0, 0);
            sa4[n] = __builtin_amdgcn_mfma_f32_16x16x32_bf16(k1, qf1, sa4[n], 0, 0, 0);
        }
        if (cb) {
            #pragma unroll
            for (int n = 0; n < 4; n++) {
                int rb = (n*16 + lr) * 128;
                bf16x8 k0 = *reinterpret_cast<const bf16x8*>(Kc + rb + (( 0 + hi*16) ^ swp));
                bf16x8 k1 = *reinterpret_cast<const bf16x8*>(Kc + rb + ((64 + hi*16) ^ swp));
                sb4[n] = __builtin_amdgcn_mfma_f32_16x16x32_bf16(k0, qf0, sb4[n], 0, 0, 0);
                sb4[n] = __builtin_amdgcn_mfma_f32_16x16x32_bf16(k1, qf1, sb4[n], 0, 0, 0);
            }
        }
        __builtin_amdgcn_s_setprio(0);

        if (kba + 63 > qrow) {
            #pragma unroll
            for (int n = 0; n < 4; n++)
                #pragma unroll
                for (int r = 0; r < 4; r++)
                    if (kba + n*16 + hi*4 + r > qg) sa4[n][r] = -3e38f;
        }
        if (cb && kbb + 63 > qrow) {
            #pragma unroll
            for (int n = 0; n < 4; n++)
                #pragma unroll
                for (int r = 0; r < 4; r++)
                    if (kbb + n*16 + hi*4 + r > qg) sb4[n][r] = -3e38f;
        }

        // per-q-row max over the pair: packed-f32 tree
        f32x2 m2;
        {
            f32x2 x0 = __builtin_shufflevector(sa4[0], sa4[0], 0, 1);
            f32x2 x1 = __builtin_shufflevector(sa4[0], sa4[0], 2, 3);
            m2 = __builtin_elementwise_max(x0, x1);
            #pragma unroll
            for (int n = 1; n < 4; n++) {
                f32x2 y0 = __builtin_shufflevector(sa4[n], sa4[n], 0, 1);
                f32x2 y1 = __builtin_shufflevector(sa4[n], sa4[n], 2, 3);
                m2 = __builtin_elementwise_max(m2, __builtin_elementwise_max(y0, y1));
            }
            if (cb) {
                #pragma unroll
                for (int n = 0; n < 4; n++) {
                    f32x2 y0 = __builtin_shufflevector(sb4[n], sb4[n], 0, 1);
                    f32x2 y1 = __builtin_shufflevector(sb4[n], sb4[n], 2, 3);
                    m2 = __builtin_elementwise_max(m2, __builtin_elementwise_max(y0, y1));
                }
            }
        }
        float rm = fmaxf(m2[0], m2[1]);
        rm = fmaxf(rm, __shfl_xor(rm, 16, 64));
        rm = fmaxf(rm, __shfl_xor(rm, 32, 64));
        if (!__all(rm - mS <= THR)) {
            float newm = fmaxf(mS, rm);
            float al = exp2f(sc * (mS - newm));
            mS = newm;
            lS *= al;
            #pragma unroll
            for (int r = 0; r < 4; r++) {
                float alr = __shfl(al, hi*4 + r, 64);
                o[0][r] *= alr; o[1][r] *= alr; o[2][r] *= alr; o[3][r] *= alr;
            }
        }
        const float c0 = sc * mS;
        const f32x2 sc2 = {sc, sc};
        const f32x2 cc2 = {-c0, -c0};
        f32x2 rs2 = {0.f, 0.f};

        #pragma unroll
        for (int n = 0; n < 4; n++) {
            f32x2 lo = __builtin_shufflevector(sa4[n], sa4[n], 0, 1);
            f32x2 hif = __builtin_shufflevector(sa4[n], sa4[n], 2, 3);
            lo  = __builtin_elementwise_fma(lo,  sc2, cc2);
            hif = __builtin_elementwise_fma(hif, sc2, cc2);
            f32x2 plo = {exp2f(lo[0]),  exp2f(lo[1])};
            f32x2 phi = {exp2f(hif[0]), exp2f(hif[1])};
            rs2 += plo + phi;
            ushort4 u;
            u.x = f2bf(plo[0]); u.y = f2bf(plo[1]);
            u.z = f2bf(phi[0]); u.w = f2bf(phi[1]);
            *reinterpret_cast<ushort4*>(Pw + (lr*128 + ((n*32 + hi*8) ^ swp))) = u;
        }
        ushort4 ub[4];
        if (cb) {
            #pragma unroll
            for (int n = 0; n < 4; n++) {
                f32x2 lo = __builtin_shufflevector(sb4[n], sb4[n], 0, 1);
                f32x2 hif = __builtin_shufflevector(sb4[n], sb4[n], 2, 3);
                lo  = __builtin_elementwise_fma(lo,  sc2, cc2);
                hif = __builtin_elementwise_fma(hif, sc2, cc2);
                f32x2 plo = {exp2f(lo[0]),  exp2f(lo[1])};
                f32x2 phi = {exp2f(hif[0]), exp2f(hif[1])};
                rs2 += plo + phi;
                ub[n].x = f2bf(plo[0]); ub[n].y = f2bf(plo[1]);
                ub[n].z = f2bf(phi[0]); ub[n].w = f2bf(phi[1]);
            }
        }
        float rs = rs2[0] + rs2[1];
        rs += __shfl_xor(rs, 16, 64);
        rs += __shfl_xor(rs, 32, 64);
        lS += rs;

        {
            bf16x8 pa0 = *reinterpret_cast<const bf16x8*>(Pw + (lr*128 + (( 0 + hi*16) ^ swp)));
            bf16x8 pa1 = *reinterpret_cast<const bf16x8*>(Pw + (lr*128 + ((64 + hi*16) ^ swp)));
            __builtin_amdgcn_s_setprio(1);
            #pragma unroll
            for (int nd = 0; nd < 4; nd++) {
                int rb = (nd*16 + lr) * 128;
                bf16x8 v0 = *reinterpret_cast<const bf16x8*>(Va + rb + (( 0 + hi*16) ^ swp));
                bf16x8 v1 = *reinterpret_cast<const bf16x8*>(Va + rb + ((64 + hi*16) ^ swp));
                o[nd] = __builtin_amdgcn_mfma_f32_16x16x32_bf16(pa0, v0, o[nd], 0, 0, 0);
                o[nd] = __builtin_amdgcn_mfma_f32_16x16x32_bf16(pa1, v1, o[nd], 0, 0, 0);
            }
            __builtin_amdgcn_s_setprio(0);
        }
        if (cb) {
            #pragma unroll
            for (int n = 0; n < 4; n++)
                *reinterpret_cast<ushort4*>(Pw + (lr*128 + ((n*32 + hi*8) ^ swp))) = ub[n];
            bf16x8 pa0 = *reinterpret_cast<const bf16x8*>(Pw + (lr*128 + (( 0 + hi*16) ^ swp)));
            bf16x8 pa1 = *reinterpret_cast<const bf16x8*>(Pw + (lr*128 + ((64 + hi*16) ^ swp)));
            __builtin_amdgcn_s_setprio(1);
            #pragma unroll
            for (int nd = 0; nd < 4; nd++) {
                int rb = (nd*16 + lr) * 128;
                bf16x8 v0 = *reinterpret_cast<const bf16x8*>(Vc + rb + (( 0 + hi*16) ^ swp));
                bf16x8 v1 = *reinterpret_cast<const bf16x8*>(Vc + rb + ((64 + hi*16) ^ swp));
                o[nd] = __builtin_amdgcn_mfma_f32_16x16x32_bf16(pa0, v0, o[nd], 0, 0, 0);
                o[nd] = __builtin_amdgcn_mfma_f32_16x16x32_bf16(pa1, v1, o[nd], 0, 0, 0);
            }
            __builtin_amdgcn_s_setprio(0);
        }
        __syncthreads();
    }

    float inv = 1.0f / lS;
    int b = bh >> 4, h = bh & 15;
    #pragma unroll
    for (int r = 0; r < 4; r++) {
        float invr = __shfl(inv, hi*4 + r, 64);
        int t = qrow + hi*4 + r;
        #pragma unroll
        for (int nd = 0; nd < 4; nd++) {
            float val = o[nd][r] * invr;
            ao[((size_t)b*TT + t)*D_MODEL + h*HD + nd*16 + lr] = f2bf(val);
        }
    }
}

extern "C" void kernel_launch(void* const* d_in, const int* in_sizes, int n_in,
                              void* d_out, int out_size, void* d_ws, size_t ws_size,
                              hipStream_t stream) {
    const float* x     = (const float*)d_in[0];
    const float* w_qkv = (const float*)d_in[1];
    const float* b_qkv = (const float*)d_in[2];
    const float* w_out = (const float*)d_in[3];
    const float* b_out = (const float*)d_in[4];
    float* out = (float*)d_out;

    char* ws = (char*)d_ws;
    unsigned short* xbf   = (unsigned short*)(ws);                         // 16 MB
    unsigned short* wqkvb = (unsigned short*)(ws + (size_t)16777216);      // 6 MB
    unsigned short* woutb = (unsigned short*)(ws + (size_t)23068672);      // 2 MB
    unsigned short* qb    = (unsigned short*)(ws + (size_t)25165824);      // 16 MB
    unsigned short* kb    = (unsigned short*)(ws + (size_t)41943040);      // 16 MB
    unsigned short* vtb   = (unsigned short*)(ws + (size_t)58720256);      // 16 MB
    unsigned short* aob   = xbf;  // alias: x_bf16 dead after gemm_qkv

    cast3_kernel<<<(N4_X + N4_WQ + N4_WO)/256, 256, 0, stream>>>(x, w_qkv, w_out, xbf, wqkvb, woutb);

    gemm_qkv<<<(MM/256)*(NQKV/128), 512, 0, stream>>>(xbf, wqkvb, b_qkv, qb, kb, vtb);
    attn_kernel<<<dim3(BB*NHEADS, TT/128), 512, 0, stream>>>(qb, kb, vtb, aob);
    gemm_out<<<(MM/256)*(D_MODEL/128), 512, 0, stream>>>(aob, woutb, b_out, out);
}